// Round 2
// baseline (153.759 us; speedup 1.0000x reference)
//
#include <hip/hip_runtime.h>
#include <hip/hip_bf16.h>

#define BB 8
#define NN 4096
#define DD 3
#define HH 256
#define KOUT 1024
#define NC 64   // 63 clusters padded to 64

// ---------------- K1: per-point q,k,v projections ----------------
__global__ __launch_bounds__(256) void k_proj(
    const float* __restrict__ x,
    const float* __restrict__ Wq, const float* __restrict__ bq,
    const float* __restrict__ Wk, const float* __restrict__ bk,
    const float* __restrict__ Wv, const float* __restrict__ bv,
    float4* __restrict__ k4, float4* __restrict__ v4, float4* __restrict__ q4)
{
    int t = blockIdx.x * 256 + threadIdx.x;   // 0 .. B*N-1
    if (t >= BB * NN) return;
    int b = t >> 12, n = t & (NN - 1);

    float x0 = x[t * 3 + 0];
    float x1 = x[t * 3 + 1];
    float x2 = x[t * 3 + 2];

    // k = x @ Wk.T + bk  (Wk row-major [3][3])
    float k0 = bk[0] + x0 * Wk[0] + x1 * Wk[1] + x2 * Wk[2];
    float k1 = bk[1] + x0 * Wk[3] + x1 * Wk[4] + x2 * Wk[5];
    float k2 = bk[2] + x0 * Wk[6] + x1 * Wk[7] + x2 * Wk[8];
    k4[t] = make_float4(k0, k1, k2, 0.f);

    float v0 = bv[0] + x0 * Wv[0] + x1 * Wv[1] + x2 * Wv[2];
    float v1 = bv[1] + x0 * Wv[3] + x1 * Wv[4] + x2 * Wv[5];
    float v2 = bv[2] + x0 * Wv[6] + x1 * Wv[7] + x2 * Wv[8];
    v4[t] = make_float4(v0, v1, v2, 0.f);

    if (n < KOUT) {
        float q0 = bq[0] + x0 * Wq[0] + x1 * Wq[1] + x2 * Wq[2];
        float q1 = bq[1] + x0 * Wq[3] + x1 * Wq[4] + x2 * Wq[5];
        float q2 = bq[2] + x0 * Wq[6] + x1 * Wq[7] + x2 * Wq[8];
        q4[b * KOUT + n] = make_float4(q0, q1, q2, 0.f);
    }
}

// ---------------- K2: per-batch cluster member lists (LDS hist + scan + scatter) ----------------
__global__ __launch_bounds__(256) void k_build(
    const int* __restrict__ labels,
    int* __restrict__ counts, int* __restrict__ offsets, int* __restrict__ members)
{
    int b = blockIdx.x;
    __shared__ int hist[NC];
    __shared__ int offs[NC];
    __shared__ int cur[NC];
    int tid = threadIdx.x;
    if (tid < NC) hist[tid] = 0;
    __syncthreads();

    const int* lb = labels + b * NN;
    for (int i = tid; i < NN; i += 256) {
        int l = lb[i];
        if (l >= 0) atomicAdd(&hist[l], 1);
    }
    __syncthreads();
    if (tid == 0) {
        int run = 0;
        for (int c = 0; c < NC; c++) { offs[c] = run; run += hist[c]; }
    }
    __syncthreads();
    if (tid < NC) {
        cur[tid] = offs[tid];
        counts[b * NC + tid]  = hist[tid];
        offsets[b * NC + tid] = offs[tid];
    }
    __syncthreads();
    for (int i = tid; i < NN; i += 256) {
        int l = lb[i];
        if (l >= 0) {
            int p = atomicAdd(&cur[l], 1);
            members[b * NN + p] = i;
        }
    }
}

// ---------------- K3: per-row clustered softmax-attention + MLP ----------------
__global__ __launch_bounds__(64) void k_attn(
    const int* __restrict__ labels,
    const float4* __restrict__ k4, const float4* __restrict__ v4,
    const float4* __restrict__ q4,
    const int* __restrict__ counts, const int* __restrict__ offsets,
    const int* __restrict__ members,
    const float* __restrict__ Wo, const float* __restrict__ bo,
    const float* __restrict__ W1, const float* __restrict__ b1,
    const float* __restrict__ W2, const float* __restrict__ b2,
    float* __restrict__ out)
{
    __shared__ float4 sW1[HH];   // (w1_0, w1_1, w1_2, b1) per hidden unit
    __shared__ float4 sW2[HH];   // (w2 col d=0,1,2, pad)
    int tid = threadIdx.x;
    for (int j = tid; j < HH; j += 64) {
        sW1[j] = make_float4(W1[j * 3 + 0], W1[j * 3 + 1], W1[j * 3 + 2], b1[j]);
        sW2[j] = make_float4(W2[j], W2[HH + j], W2[2 * HH + j], 0.f);
    }
    __syncthreads();

    int row = blockIdx.x * 64 + tid;          // 0 .. B*KOUT-1
    int b = row >> 10, n = row & (KOUT - 1);
    int l = labels[b * NN + n];

    float c0 = 0.f, c1 = 0.f, c2 = 0.f;
    if (l >= 0) {
        float4 q = q4[row];
        const float scale = 0.5773502691896258f;  // 1/sqrt(3)
        int base = offsets[b * NC + l];
        int cnt  = counts[b * NC + l];
        const int* mem = members + b * NN + base;
        const float4* kb = k4 + b * NN;
        const float4* vb = v4 + b * NN;

        float smax = -1e30f;
        for (int i = 0; i < cnt; i++) {
            float4 k = kb[mem[i]];
            float s = (q.x * k.x + q.y * k.y + q.z * k.z) * scale;
            smax = fmaxf(smax, s);
        }
        float denom = 0.f;
        for (int i = 0; i < cnt; i++) {
            int idx = mem[i];
            float4 k = kb[idx];
            float s = (q.x * k.x + q.y * k.y + q.z * k.z) * scale;
            float w = __expf(s - smax);
            float4 v = vb[idx];
            denom += w;
            c0 += w * v.x; c1 += w * v.y; c2 += w * v.z;
        }
        float inv = 1.f / denom;
        c0 *= inv; c1 *= inv; c2 *= inv;
    }

    // out_proj: out = ctx @ Wo.T + bo
    float o0 = bo[0] + c0 * Wo[0] + c1 * Wo[1] + c2 * Wo[2];
    float o1 = bo[1] + c0 * Wo[3] + c1 * Wo[4] + c2 * Wo[5];
    float o2 = bo[2] + c0 * Wo[6] + c1 * Wo[7] + c2 * Wo[8];

    float y0 = b2[0], y1 = b2[1], y2 = b2[2];
    #pragma unroll 4
    for (int j = 0; j < HH; j++) {
        float4 w1 = sW1[j];
        float h = fmaxf(w1.x * o0 + w1.y * o1 + w1.z * o2 + w1.w, 0.f);
        float4 w2 = sW2[j];
        y0 += h * w2.x; y1 += h * w2.y; y2 += h * w2.z;
    }

    out[row * 3 + 0] = y0;
    out[row * 3 + 1] = y1;
    out[row * 3 + 2] = y2;
}

extern "C" void kernel_launch(void* const* d_in, const int* in_sizes, int n_in,
                              void* d_out, int out_size, void* d_ws, size_t ws_size,
                              hipStream_t stream) {
    const float* x      = (const float*)d_in[0];
    const int*   labels = (const int*)d_in[1];
    const float* Wq = (const float*)d_in[2];
    const float* bq = (const float*)d_in[3];
    const float* Wk = (const float*)d_in[4];
    const float* bk = (const float*)d_in[5];
    const float* Wv = (const float*)d_in[6];
    const float* bv = (const float*)d_in[7];
    const float* Wo = (const float*)d_in[8];
    const float* bo = (const float*)d_in[9];
    const float* W1 = (const float*)d_in[10];
    const float* b1 = (const float*)d_in[11];
    const float* W2 = (const float*)d_in[12];
    const float* b2 = (const float*)d_in[13];
    float* out = (float*)d_out;

    // workspace layout (all 16B-aligned first)
    float4* k4 = (float4*)d_ws;            // B*N
    float4* v4 = k4 + BB * NN;             // B*N
    float4* q4 = v4 + BB * NN;             // B*KOUT
    int* counts  = (int*)(q4 + BB * KOUT); // B*NC
    int* offsets = counts + BB * NC;       // B*NC
    int* members = offsets + BB * NC;      // B*N

    k_proj<<<(BB * NN) / 256, 256, 0, stream>>>(x, Wq, bq, Wk, bk, Wv, bv, k4, v4, q4);
    k_build<<<BB, 256, 0, stream>>>(labels, counts, offsets, members);
    k_attn<<<(BB * KOUT) / 64, 64, 0, stream>>>(labels, k4, v4, q4, counts, offsets, members,
                                                Wo, bo, W1, b1, W2, b2, out);
}

// Round 3
// 98.892 us; speedup vs baseline: 1.5548x; 1.5548x over previous
//
#include <hip/hip_runtime.h>

#define BB 8
#define NN 4096
#define HH 256
#define KOUT 1024
#define NC 64   // 63 clusters padded to 64

// ---------------- K1: per-batch fused projections + cluster member lists ----------------
// One block per batch (8 blocks x 1024 threads). Proj work is tiny (4 pts/thread);
// fusing drops one kernel launch from the graph.
__global__ __launch_bounds__(1024) void k_prep(
    const float* __restrict__ x, const int* __restrict__ labels,
    const float* __restrict__ Wq, const float* __restrict__ bq,
    const float* __restrict__ Wk, const float* __restrict__ bk,
    const float* __restrict__ Wv, const float* __restrict__ bv,
    float4* __restrict__ k4, float4* __restrict__ v4, float4* __restrict__ q4,
    int* __restrict__ counts, int* __restrict__ offsets, int* __restrict__ members)
{
    int b = blockIdx.x;
    int tid = threadIdx.x;
    __shared__ int hist[NC], cur[NC];
    if (tid < NC) hist[tid] = 0;
    __syncthreads();

    const int* lb = labels + b * NN;
    const float* xb = x + b * NN * 3;

    #pragma unroll
    for (int kk = 0; kk < 4; kk++) {
        int i = kk * 1024 + tid;
        float x0 = xb[i * 3 + 0];
        float x1 = xb[i * 3 + 1];
        float x2 = xb[i * 3 + 2];

        float k0 = bk[0] + x0 * Wk[0] + x1 * Wk[1] + x2 * Wk[2];
        float k1 = bk[1] + x0 * Wk[3] + x1 * Wk[4] + x2 * Wk[5];
        float k2 = bk[2] + x0 * Wk[6] + x1 * Wk[7] + x2 * Wk[8];
        k4[b * NN + i] = make_float4(k0, k1, k2, 0.f);

        float v0 = bv[0] + x0 * Wv[0] + x1 * Wv[1] + x2 * Wv[2];
        float v1 = bv[1] + x0 * Wv[3] + x1 * Wv[4] + x2 * Wv[5];
        float v2 = bv[2] + x0 * Wv[6] + x1 * Wv[7] + x2 * Wv[8];
        v4[b * NN + i] = make_float4(v0, v1, v2, 0.f);

        if (i < KOUT) {
            float q0 = bq[0] + x0 * Wq[0] + x1 * Wq[1] + x2 * Wq[2];
            float q1 = bq[1] + x0 * Wq[3] + x1 * Wq[4] + x2 * Wq[5];
            float q2 = bq[2] + x0 * Wq[6] + x1 * Wq[7] + x2 * Wq[8];
            q4[b * KOUT + i] = make_float4(q0, q1, q2, 0.f);
        }

        int l = lb[i];
        if (l >= 0) atomicAdd(&hist[l], 1);
    }
    __syncthreads();

    // wave 0: Kogge-Stone exclusive scan over 64 cluster counts
    if (tid < 64) {
        int v = hist[tid];
        int s = v;
        #pragma unroll
        for (int d = 1; d < 64; d <<= 1) {
            int o = __shfl_up(s, d, 64);
            if (tid >= d) s += o;
        }
        int e = s - v;
        cur[tid] = e;
        counts[b * NC + tid]  = v;
        offsets[b * NC + tid] = e;
    }
    __syncthreads();

    #pragma unroll
    for (int kk = 0; kk < 4; kk++) {
        int i = kk * 1024 + tid;
        int l = lb[i];
        if (l >= 0) {
            int p = atomicAdd(&cur[l], 1);
            members[b * NN + p] = i;
        }
    }
}

// ---------------- K2: wave-per-row clustered softmax-attention + MLP ----------------
// 8192 rows -> 8192 waves (2048 blocks x 256 threads). Members strided over 64
// lanes (~1-2 gathers/lane from L1/L2-resident k4/v4); shuffle-xor reductions.
__global__ __launch_bounds__(256) void k_attn(
    const int* __restrict__ labels,
    const float4* __restrict__ k4, const float4* __restrict__ v4,
    const float4* __restrict__ q4,
    const int* __restrict__ counts, const int* __restrict__ offsets,
    const int* __restrict__ members,
    const float* __restrict__ Wo, const float* __restrict__ bo,
    const float* __restrict__ W1, const float* __restrict__ b1,
    const float* __restrict__ W2, const float* __restrict__ b2,
    float* __restrict__ out)
{
    int row  = (blockIdx.x * 256 + threadIdx.x) >> 6;   // 0 .. B*KOUT-1
    int lane = threadIdx.x & 63;
    int b = row >> 10, n = row & (KOUT - 1);
    int l = labels[b * NN + n];

    float c0 = 0.f, c1 = 0.f, c2 = 0.f;
    if (l >= 0) {
        float4 q = q4[row];
        const float scale = 0.5773502691896258f;  // 1/sqrt(3)
        int base = offsets[b * NC + l];
        int cnt  = counts[b * NC + l];
        const int* mem = members + b * NN + base;
        const float4* kb = k4 + b * NN;
        const float4* vb = v4 + b * NN;

        // pass 1: wave max of scores
        float m = -1e30f;
        for (int i = lane; i < cnt; i += 64) {
            float4 k = kb[mem[i]];
            float s = (q.x * k.x + q.y * k.y + q.z * k.z) * scale;
            m = fmaxf(m, s);
        }
        #pragma unroll
        for (int d = 32; d > 0; d >>= 1) m = fmaxf(m, __shfl_xor(m, d, 64));

        // pass 2: exp-weighted accumulation
        float denom = 0.f;
        for (int i = lane; i < cnt; i += 64) {
            int idx = mem[i];
            float4 k = kb[idx];
            float s = (q.x * k.x + q.y * k.y + q.z * k.z) * scale;
            float w = __expf(s - m);
            float4 v = vb[idx];
            denom += w;
            c0 += w * v.x; c1 += w * v.y; c2 += w * v.z;
        }
        #pragma unroll
        for (int d = 32; d > 0; d >>= 1) {
            denom += __shfl_xor(denom, d, 64);
            c0    += __shfl_xor(c0, d, 64);
            c1    += __shfl_xor(c1, d, 64);
            c2    += __shfl_xor(c2, d, 64);
        }
        float inv = 1.f / denom;
        c0 *= inv; c1 *= inv; c2 *= inv;
    }

    // out_proj (lane-uniform, cheap)
    float o0 = bo[0] + c0 * Wo[0] + c1 * Wo[1] + c2 * Wo[2];
    float o1 = bo[1] + c0 * Wo[3] + c1 * Wo[4] + c2 * Wo[5];
    float o2 = bo[2] + c0 * Wo[6] + c1 * Wo[7] + c2 * Wo[8];

    // MLP: 4 hidden units per lane, coalesced W1/W2 reads (L2-resident)
    float y0 = 0.f, y1 = 0.f, y2 = 0.f;
    #pragma unroll
    for (int t = 0; t < 4; t++) {
        int j = lane + 64 * t;
        float h = fmaxf(W1[j * 3 + 0] * o0 + W1[j * 3 + 1] * o1 + W1[j * 3 + 2] * o2 + b1[j], 0.f);
        y0 += h * W2[j];
        y1 += h * W2[HH + j];
        y2 += h * W2[2 * HH + j];
    }
    #pragma unroll
    for (int d = 32; d > 0; d >>= 1) {
        y0 += __shfl_xor(y0, d, 64);
        y1 += __shfl_xor(y1, d, 64);
        y2 += __shfl_xor(y2, d, 64);
    }
    if (lane == 0) {
        out[row * 3 + 0] = y0 + b2[0];
        out[row * 3 + 1] = y1 + b2[1];
        out[row * 3 + 2] = y2 + b2[2];
    }
}

extern "C" void kernel_launch(void* const* d_in, const int* in_sizes, int n_in,
                              void* d_out, int out_size, void* d_ws, size_t ws_size,
                              hipStream_t stream) {
    const float* x      = (const float*)d_in[0];
    const int*   labels = (const int*)d_in[1];
    const float* Wq = (const float*)d_in[2];
    const float* bq = (const float*)d_in[3];
    const float* Wk = (const float*)d_in[4];
    const float* bk = (const float*)d_in[5];
    const float* Wv = (const float*)d_in[6];
    const float* bv = (const float*)d_in[7];
    const float* Wo = (const float*)d_in[8];
    const float* bo = (const float*)d_in[9];
    const float* W1 = (const float*)d_in[10];
    const float* b1 = (const float*)d_in[11];
    const float* W2 = (const float*)d_in[12];
    const float* b2 = (const float*)d_in[13];
    float* out = (float*)d_out;

    // workspace layout (16B-aligned first)
    float4* k4 = (float4*)d_ws;            // B*N
    float4* v4 = k4 + BB * NN;             // B*N
    float4* q4 = v4 + BB * NN;             // B*KOUT
    int* counts  = (int*)(q4 + BB * KOUT); // B*NC
    int* offsets = counts + BB * NC;       // B*NC
    int* members = offsets + BB * NC;      // B*N

    k_prep<<<BB, 1024, 0, stream>>>(x, labels, Wq, bq, Wk, bk, Wv, bv,
                                    k4, v4, q4, counts, offsets, members);
    k_attn<<<(BB * KOUT * 64) / 256, 256, 0, stream>>>(labels, k4, v4, q4, counts, offsets, members,
                                                       Wo, bo, W1, b1, W2, b2, out);
}